// Round 4
// baseline (259.470 us; speedup 1.0000x reference)
//
#include <hip/hip_runtime.h>

// ICFM: out[s] = sum_{t: seg_ids[t]==s} ( intr_W[intr_idxs[t]] / intr_divs[t]
//                                         * dot(vecs[f0[t]], vecs[f1[t]]) + intr_b[0] )
// T = 1048576, NUM_SEGMENTS = 16384, VEC = 64 floats (256 B/row), table 128 MB.
//
// R2 lesson: the 4-deep __shfl_xor chain (LDS pipe, dependent lgkm waits) was
// the serializer. R3: no cross-lane reduction at all — each lane adds its
// weighted PARTIAL dot (+ b/16) into bins[seg-seg0][lane16] via fire-and-forget
// LDS atomicAdd. Dependency chain per interaction: load -> dot4 -> fmac ->
// ds_atomic (no return, no wait). Columns reduced once per block at flush.

#define BLOCK 256
#define CHUNK 512   // interactions per block (T divisible: 2048 blocks)
#define SMAX  64    // LDS segment window (avg span ~8; global-atomic fallback)
#define U     4     // interactions per 16-lane group per iteration

__global__ __launch_bounds__(BLOCK) void icfm_kernel(
    const int*   __restrict__ intr_idxs,
    const float* __restrict__ intr_divs,
    const int*   __restrict__ feat_idxs,   // [T*2] flat pairs
    const int*   __restrict__ seg_ids,     // sorted
    const float4* __restrict__ vecs,       // [N_FEATS][16] float4
    const float* __restrict__ intr_W,
    const float* __restrict__ intr_b,
    float*       __restrict__ out,
    int n, int num_segments)
{
    __shared__ float bins[SMAX][16];
    {
        float* bf = &bins[0][0];
        for (int i = threadIdx.x; i < SMAX * 16; i += BLOCK) bf[i] = 0.0f;
    }
    __syncthreads();

    const int chunk_start = blockIdx.x * CHUNK;
    const int first_t = chunk_start < n ? chunk_start : (n - 1);
    const int seg0 = seg_ids[first_t];
    const float b16 = intr_b[0] * (1.0f / 16.0f);   // per-lane share of bias

    const int lane16 = threadIdx.x & 15;
    const int group  = threadIdx.x >> 4;   // 16 groups per block

    for (int i = 0; i < CHUNK; i += 16 * U) {
        const int tb = chunk_start + i + group;

        // ---- load phase: issue all gathers before any consumption ----
        float4 a[U], c[U];
        float  w[U], dv[U];
        int    sg[U];
        bool   ok[U];
        #pragma unroll
        for (int u = 0; u < U; ++u) {
            int t = tb + 16 * u;
            ok[u] = (t < n);
            int tc = ok[u] ? t : first_t;               // safe clamp
            int f0 = __builtin_nontemporal_load(&feat_idxs[2 * tc]);
            int f1 = __builtin_nontemporal_load(&feat_idxs[2 * tc + 1]);
            a[u]  = vecs[(size_t)f0 * 16 + lane16];
            c[u]  = vecs[(size_t)f1 * 16 + lane16];
            w[u]  = intr_W[__builtin_nontemporal_load(&intr_idxs[tc])];
            dv[u] = __builtin_nontemporal_load(&intr_divs[tc]);
            sg[u] = __builtin_nontemporal_load(&seg_ids[tc]);
        }

        // ---- compute phase: no cross-lane ops, fire-and-forget atomics ----
        #pragma unroll
        for (int u = 0; u < U; ++u) {
            if (!ok[u]) continue;
            float d = a[u].x * c[u].x + a[u].y * c[u].y
                    + a[u].z * c[u].z + a[u].w * c[u].w;
            float val = w[u] / dv[u] * d + b16;         // per-lane partial
            int local = sg[u] - seg0;
            if ((unsigned)local < (unsigned)SMAX)
                atomicAdd(&bins[local][lane16], val);   // LDS atomic, no return
            else
                atomicAdd(&out[sg[u]], val);            // rare overflow fallback
        }
    }
    __syncthreads();

    // ---- flush: column-reduce each bin, one global atomic per bin ----
    if (threadIdx.x < SMAX) {
        float v = 0.0f;
        #pragma unroll
        for (int j = 0; j < 16; ++j) v += bins[threadIdx.x][j];
        int s = seg0 + threadIdx.x;
        if (v != 0.0f && s < num_segments)
            atomicAdd(&out[s], v);
    }
}

extern "C" void kernel_launch(void* const* d_in, const int* in_sizes, int n_in,
                              void* d_out, int out_size, void* d_ws, size_t ws_size,
                              hipStream_t stream) {
    const int*    intr_idxs = (const int*)   d_in[0];
    const float*  intr_divs = (const float*) d_in[1];
    const int*    feat_idxs = (const int*)   d_in[2];
    const int*    seg_ids   = (const int*)   d_in[3];
    const float4* vecs      = (const float4*)d_in[4];
    const float*  intr_W    = (const float*) d_in[5];
    const float*  intr_b    = (const float*) d_in[6];
    float* out = (float*)d_out;

    const int n = in_sizes[0];             // T
    const int num_segments = out_size;     // 16384

    // d_out is re-poisoned to 0xAA before every timed launch
    (void)hipMemsetAsync(d_out, 0, (size_t)out_size * sizeof(float), stream);

    const int grid = (n + CHUNK - 1) / CHUNK;
    icfm_kernel<<<grid, BLOCK, 0, stream>>>(intr_idxs, intr_divs, feat_idxs,
                                            seg_ids, vecs, intr_W, intr_b,
                                            out, n, num_segments);
}